// Round 5
// baseline (19971.854 us; speedup 1.0000x reference)
//
#include <hip/hip_runtime.h>

// ---------------------------------------------------------------------------
// 2-layer LSTM LM forward, MI355X persistent-kernel design, round 5.
//
//   round r (1..4097): layer0 computes step r, layer1 computes step r-1.
//   h travels as TAG-EMBEDDED u64 words ((round<<32)|bf16x2), RELAXED agent
//   atomics (R3 protocol). New in R5: single block barrier per round —
//   parity-double-buffered v staging in LDS, per-wave LDS gate flags, and a
//   dedicated gate wave (wave 7) that polls nothing, computes both layers'
//   gates and publishes while other waves already poll the next round.
// ---------------------------------------------------------------------------

#define T_SEQ 4096
#define HID   1024
#define EMBD  512
#define VOCAB 50257
#define NBLK  256
#define TPB   512
#define NPOLL 448    // threads 0..447 poll+stage; wave 7 is the gate wave
#define UB    4      // hidden units per block per layer
#define NSEG0 48     // (EMBD+HID)/32 k-segments, layer 0
#define NSEG1 64     // (HID+HID)/32  k-segments, layer 1

// workspace layout (32-bit word offsets)
#define WS_H0T 0       // u64[2][512]: (tag<<32)|bf16pair
#define WS_H1T 2048    // u64[2][512]
#define WS_H1F 4096    // float[1024] final h1
#define WS_LOG 5120    // float[50257] logits
#define WS_LSE 55377   // float[1]

// LDS layout (bytes)
#define OFF_W0 0                   // short8[NSEG0*64] = 49152
#define OFF_W1 49152               // short8[NSEG1*64] = 65536
#define OFF_V0 114688              // 2 x (bf16[1536]) parity buffers (x || h0)
#define OFF_V1 120832              // 2 x (bf16[2048]) parity buffers (h0 || h1)
#define OFF_GP 129024              // float[7][16] gate partials (+pad)
#define OFF_B0 129536              // float[16]
#define OFF_B1 129600              // float[16]
#define OFF_GF 129664              // unsigned[8] per-wave gate flags
#define SMEM_BYTES 129696

typedef __attribute__((ext_vector_type(8))) short short8;
typedef __attribute__((ext_vector_type(4))) float f32x4;
typedef unsigned long long u64;

__device__ __forceinline__ unsigned short f2bf(float f) {
  unsigned int u = __float_as_uint(f);
  u += 0x7FFFu + ((u >> 16) & 1u);          // round-to-nearest-even
  return (unsigned short)(u >> 16);
}
__device__ __forceinline__ unsigned int pack2bf(float a, float b) {
  return (unsigned int)f2bf(a) | ((unsigned int)f2bf(b) << 16);
}
__device__ __forceinline__ float sigmoidf_(float x) {
  return 1.f / (1.f + __expf(-x));
}
__device__ __forceinline__ float tanhf_(float x) {
  return 1.f - 2.f / (__expf(2.f * x) + 1.f);
}
__device__ __forceinline__ unsigned ldsacq(const unsigned* p) {
  return __hip_atomic_load(p, __ATOMIC_ACQUIRE, __HIP_MEMORY_SCOPE_WORKGROUP);
}

// 16 MFMA k-segments of the matvec. A = v replicated across the 16 rows
// (broadcast LDS read; any lane->k map cancels between A and B since both
// were packed with the same map). B = 16 gate-rows as columns from LDS.
// D: col = lane&15 = gate-row (HW-verified C/D layout).
__device__ __forceinline__ void mmv(const short8* vf, const short8* wf,
                                    int s0, int grp, float* gout, int lane) {
  f32x4 a0 = {0.f, 0.f, 0.f, 0.f};
  f32x4 a1 = a0, a2 = a0, a3 = a0;
#pragma unroll
  for (int i = 0; i < 16; ++i) {
    const int seg = s0 + i;
    short8 av = vf[seg * 4 + grp];
    short8 bv = wf[seg * 64 + lane];
    if ((i & 3) == 0)      a0 = __builtin_amdgcn_mfma_f32_16x16x32_bf16(av, bv, a0, 0, 0, 0);
    else if ((i & 3) == 1) a1 = __builtin_amdgcn_mfma_f32_16x16x32_bf16(av, bv, a1, 0, 0, 0);
    else if ((i & 3) == 2) a2 = __builtin_amdgcn_mfma_f32_16x16x32_bf16(av, bv, a2, 0, 0, 0);
    else                   a3 = __builtin_amdgcn_mfma_f32_16x16x32_bf16(av, bv, a3, 0, 0, 0);
  }
  f32x4 s = (a0 + a1) + (a2 + a3);
  if (lane < 16) gout[lane] = s[0];
}

// ---------------------------------------------------------------------------
__global__ __launch_bounds__(TPB, 1) void reset_kernel(
    const float* __restrict__ h0in, unsigned int* __restrict__ ws) {
  const int tid = threadIdx.x;
  u64* H0T = reinterpret_cast<u64*>(ws + WS_H0T);
  u64* H1T = reinterpret_cast<u64*>(ws + WS_H1T);
  // slot 0 <- initial hidden states with tag 0; slot 1 <- INVALID tag
  // (kills the cross-replay stale-tag race at the final rounds). Agent-scope
  // stores so the scan's L2-bypassing polls are guaranteed to see them.
  const u64 w0 = (u64)pack2bf(h0in[2 * tid], h0in[2 * tid + 1]);
  const u64 w1 = (u64)pack2bf(h0in[HID + 2 * tid], h0in[HID + 2 * tid + 1]);
  __hip_atomic_store(&H0T[tid], w0, __ATOMIC_RELAXED, __HIP_MEMORY_SCOPE_AGENT);
  __hip_atomic_store(&H1T[tid], w1, __ATOMIC_RELAXED, __HIP_MEMORY_SCOPE_AGENT);
  __hip_atomic_store(&H0T[512 + tid], 0xFFFFFFFF00000000ULL, __ATOMIC_RELAXED, __HIP_MEMORY_SCOPE_AGENT);
  __hip_atomic_store(&H1T[512 + tid], 0xFFFFFFFF00000000ULL, __ATOMIC_RELAXED, __HIP_MEMORY_SCOPE_AGENT);
}

// ---------------------------------------------------------------------------
__global__ __launch_bounds__(TPB, 1) void scan_kernel(
    const int* __restrict__ tok,
    const float* __restrict__ h0in, const float* __restrict__ c0in,
    const float* __restrict__ emb,
    const float* __restrict__ wih0, const float* __restrict__ whh0,
    const float* __restrict__ bih0, const float* __restrict__ bhh0,
    const float* __restrict__ wih1, const float* __restrict__ whh1,
    const float* __restrict__ bih1, const float* __restrict__ bhh1,
    float* __restrict__ dout, unsigned int* __restrict__ ws) {
  extern __shared__ char smem[];
  short8* W0f = reinterpret_cast<short8*>(smem + OFF_W0);
  short8* W1f = reinterpret_cast<short8*>(smem + OFF_W1);
  unsigned int* v0w = reinterpret_cast<unsigned int*>(smem + OFF_V0);
  unsigned int* v1w = reinterpret_cast<unsigned int*>(smem + OFF_V1);
  const short8* v0f = reinterpret_cast<const short8*>(smem + OFF_V0);
  const short8* v1f = reinterpret_cast<const short8*>(smem + OFF_V1);
  float* gp  = reinterpret_cast<float*>(smem + OFF_GP);
  float* bs0 = reinterpret_cast<float*>(smem + OFF_B0);
  float* bs1 = reinterpret_cast<float*>(smem + OFF_B1);
  unsigned* gpflag = reinterpret_cast<unsigned*>(smem + OFF_GF);

  const int tid = threadIdx.x;
  const int bid = blockIdx.x;
  const int lane = tid & 63;
  const int w = tid >> 6;
  const int grp = lane >> 4;

  // ---- stage weights into LDS as pre-swizzled B-fragments (bf16) ----
  for (int slot = tid; slot < NSEG0 * 64; slot += TPB) {
    const int seg = slot >> 6, l = slot & 63;
    const int col = l & 15, g = l >> 4;
    const int grow = (col >> 2) * HID + bid * UB + (col & 3);
    const int k0 = seg * 32 + g * 8;
    const float* src = (k0 < EMBD) ? (wih0 + (size_t)grow * EMBD + k0)
                                   : (whh0 + (size_t)grow * HID + (k0 - EMBD));
    const float4* s4 = reinterpret_cast<const float4*>(src);
    float4 f0 = s4[0], f1 = s4[1];
    short8 pk;
    pk[0] = (short)f2bf(f0.x); pk[1] = (short)f2bf(f0.y);
    pk[2] = (short)f2bf(f0.z); pk[3] = (short)f2bf(f0.w);
    pk[4] = (short)f2bf(f1.x); pk[5] = (short)f2bf(f1.y);
    pk[6] = (short)f2bf(f1.z); pk[7] = (short)f2bf(f1.w);
    W0f[slot] = pk;
  }
  for (int slot = tid; slot < NSEG1 * 64; slot += TPB) {
    const int seg = slot >> 6, l = slot & 63;
    const int col = l & 15, g = l >> 4;
    const int grow = (col >> 2) * HID + bid * UB + (col & 3);
    const int k0 = seg * 32 + g * 8;
    const float* src = (k0 < HID) ? (wih1 + (size_t)grow * HID + k0)
                                  : (whh1 + (size_t)grow * HID + (k0 - HID));
    const float4* s4 = reinterpret_cast<const float4*>(src);
    float4 f0 = s4[0], f1 = s4[1];
    short8 pk;
    pk[0] = (short)f2bf(f0.x); pk[1] = (short)f2bf(f0.y);
    pk[2] = (short)f2bf(f0.z); pk[3] = (short)f2bf(f0.w);
    pk[4] = (short)f2bf(f1.x); pk[5] = (short)f2bf(f1.y);
    pk[6] = (short)f2bf(f1.z); pk[7] = (short)f2bf(f1.w);
    W1f[slot] = pk;
  }
  if (tid < 16) {
    const int grow = (tid >> 2) * HID + bid * UB + (tid & 3);
    bs0[tid] = bih0[grow] + bhh0[grow];
  } else if (tid < 32) {
    const int c = tid - 16;
    const int grow = (c >> 2) * HID + bid * UB + (c & 3);
    bs1[c] = bih1[grow] + bhh1[grow];
  }
  if (tid < 8) gpflag[tid] = 0u;

  // cell state lives in the gate wave (wave 7): lanes 0-3 layer0, 8-11 layer1
  float cst = 0.f;
  if (w == 7) {
    if (lane < UB) cst = c0in[bid * UB + lane];
    else if (lane >= 8 && lane < 8 + UB) cst = c0in[HID + bid * UB + (lane - 8)];
  }

  // prefetch x for round 1
  float xa = 0.f, xb = 0.f;
  if (tid < 256) {
    const float* xp = emb + (size_t)tok[0] * EMBD + tid * 2;
    xa = xp[0]; xb = xp[1];
  }

  u64* H0T = reinterpret_cast<u64*>(ws + WS_H0T);
  u64* H1T = reinterpret_cast<u64*>(ws + WS_H1T);

  __syncthreads();   // weights, biases, gpflag ready

  for (int r = 1; r <= T_SEQ + 1; ++r) {
    const int pb = r & 1;   // parity buffer for this round's v staging

    if (tid < NPOLL) {
      // x_r into parity buffer; issue x_{r+1} prefetch (drains during poll)
      if (tid < 256) {
        v0w[pb * 768 + tid] = pack2bf(xa, xb);
        const int ridx = (r < T_SEQ) ? r : (T_SEQ - 1);
        const float* xp = emb + (size_t)tok[ridx] * EMBD + tid * 2;
        xa = xp[0]; xb = xp[1];
      }

      // ---- poll up to 3 tagged ring words (combined 1024-word space) ----
      const int p0 = (r - 1) & 1;                 // h0_{r-1} slot
      const int p1 = r & 1;                       // h1_{r-2} slot ((r-2)&1)
      const unsigned tgh0 = (unsigned)(r - 1);
      const unsigned tgh1 = (unsigned)(r - 2);
      const int i0 = tid;
      const int i1 = tid + 448;
      const int i2 = (tid < 128) ? tid + 896 : tid;   // dup of i0 for tid>=128

      u64* ap0 = &H0T[p0 * 512 + i0]; unsigned tg0 = tgh0;
      u64 *ap1, *ap2; unsigned tg1, tg2;
      if (i1 < 512)      { ap1 = &H0T[p0 * 512 + i1]; tg1 = tgh0; }
      else if (r >= 2)   { ap1 = &H1T[p1 * 512 + (i1 - 512)]; tg1 = tgh1; }
      else               { ap1 = ap0; tg1 = tg0; }
      if (i2 < 512)      { ap2 = &H0T[p0 * 512 + i2]; tg2 = tgh0; }
      else if (r >= 2)   { ap2 = &H1T[p1 * 512 + (i2 - 512)]; tg2 = tgh1; }
      else               { ap2 = ap0; tg2 = tg0; }

      u64 d0 = 0, d1 = 0, d2 = 0;
      bool k0 = false, k1 = false, k2 = false;
      do {
        const u64 s0 = __hip_atomic_load(ap0, __ATOMIC_RELAXED, __HIP_MEMORY_SCOPE_AGENT);
        const u64 s1 = __hip_atomic_load(ap1, __ATOMIC_RELAXED, __HIP_MEMORY_SCOPE_AGENT);
        const u64 s2 = __hip_atomic_load(ap2, __ATOMIC_RELAXED, __HIP_MEMORY_SCOPE_AGENT);
        if (!k0 && (unsigned)(s0 >> 32) == tg0) { d0 = s0; k0 = true; }
        if (!k1 && (unsigned)(s1 >> 32) == tg1) { d1 = s1; k1 = true; }
        if (!k2 && (unsigned)(s2 >> 32) == tg2) { d2 = s2; k2 = true; }
      } while (!(k0 && k1 && k2));

      // ---- stage into parity buffers ----
      {
        const unsigned lo = (unsigned)d0;          // i0 < 512 always (h0)
        v0w[pb * 768 + 256 + i0] = lo;
        v1w[pb * 1024 + i0] = lo;
      }
      if (i1 < 512) {
        const unsigned lo = (unsigned)d1;
        v0w[pb * 768 + 256 + i1] = lo;
        v1w[pb * 1024 + i1] = lo;
      } else if (r >= 2) {
        v1w[pb * 1024 + 512 + (i1 - 512)] = (unsigned)d1;
      }
      if (tid < 128 && r >= 2) {                   // i2 >= 896 here
        v1w[pb * 1024 + 512 + (i2 - 512)] = (unsigned)d2;
      }
    }
    __syncthreads();   // the ONLY block barrier per round

    if (w < 3) {
      // layer-0 matvec waves
      if (r <= T_SEQ) {
        mmv(v0f + pb * 192, W0f, w * 16, grp, gp + w * 16, lane);
        if (lane == 0)
          __hip_atomic_store(&gpflag[w], (unsigned)r, __ATOMIC_RELEASE,
                             __HIP_MEMORY_SCOPE_WORKGROUP);
      }
    } else if (w < 7) {
      // layer-1 matvec waves
      if (r >= 2) {
        mmv(v1f + pb * 256, W1f, (w - 3) * 16, grp, gp + w * 16, lane);
        if (lane == 0)
          __hip_atomic_store(&gpflag[w], (unsigned)r, __ATOMIC_RELEASE,
                             __HIP_MEMORY_SCOPE_WORKGROUP);
      }
    } else {
      // ---- gate wave: both layers' gates + tagged publishes ----
      const unsigned ru = (unsigned)r;
      if (r <= T_SEQ) {
        while (ldsacq(&gpflag[0]) < ru || ldsacq(&gpflag[1]) < ru ||
               ldsacq(&gpflag[2]) < ru) { }
        float hv = 0.f;
        if (lane < UB) {
          const int u = lane;
          float gi = bs0[u], gf = bs0[4 + u], gg = bs0[8 + u], go = bs0[12 + u];
#pragma unroll
          for (int p = 0; p < 3; ++p) {
            gi += gp[p * 16 + u];      gf += gp[p * 16 + 4 + u];
            gg += gp[p * 16 + 8 + u];  go += gp[p * 16 + 12 + u];
          }
          const float c = sigmoidf_(gf) * cst + sigmoidf_(gi) * tanhf_(gg);
          cst = c;
          hv = sigmoidf_(go) * tanhf_(c);
          if (r == T_SEQ) {
            dout[VOCAB + bid * UB + u] = hv;              // h_n layer0
            dout[VOCAB + 2 * HID + bid * UB + u] = cst;   // c_n layer0
          }
        }
        const float a = __shfl(hv, 2 * (lane & 1));
        const float b = __shfl(hv, 2 * (lane & 1) + 1);
        if (lane < 2) {
          const u64 word = ((u64)ru << 32) | (u64)pack2bf(a, b);
          __hip_atomic_store(&H0T[(r & 1) * 512 + bid * 2 + lane], word,
                             __ATOMIC_RELAXED, __HIP_MEMORY_SCOPE_AGENT);
        }
      }
      if (r >= 2) {
        while (ldsacq(&gpflag[3]) < ru || ldsacq(&gpflag[4]) < ru ||
               ldsacq(&gpflag[5]) < ru || ldsacq(&gpflag[6]) < ru) { }
        float hv = 0.f;
        if (lane >= 8 && lane < 8 + UB) {
          const int u = lane - 8;
          float gi = bs1[u], gf = bs1[4 + u], gg = bs1[8 + u], go = bs1[12 + u];
#pragma unroll
          for (int p = 3; p < 7; ++p) {
            gi += gp[p * 16 + u];      gf += gp[p * 16 + 4 + u];
            gg += gp[p * 16 + 8 + u];  go += gp[p * 16 + 12 + u];
          }
          const float c = sigmoidf_(gf) * cst + sigmoidf_(gi) * tanhf_(gg);
          cst = c;
          hv = sigmoidf_(go) * tanhf_(c);
          if (r - 1 == T_SEQ) {
            float* h1f = reinterpret_cast<float*>(ws + WS_H1F);
            h1f[bid * UB + u] = hv;
            dout[VOCAB + HID + bid * UB + u] = hv;            // h_n layer1
            dout[VOCAB + 3 * HID + bid * UB + u] = cst;       // c_n layer1
          }
        }
        const float a = __shfl(hv, 8 + 2 * (lane & 1));
        const float b = __shfl(hv, 9 + 2 * (lane & 1));
        if (lane >= 8 && lane < 10) {
          const u64 word = ((u64)(unsigned)(r - 1) << 32) | (u64)pack2bf(a, b);
          __hip_atomic_store(&H1T[((r - 1) & 1) * 512 + bid * 2 + (lane - 8)], word,
                             __ATOMIC_RELAXED, __HIP_MEMORY_SCOPE_AGENT);
        }
      }
    }
    // no second barrier: staging for r+1 goes to the other parity buffer,
    // and gp(r+1) writes can't start until the gate wave passes barrier(r+1).
  }
}

// ---------------------------------------------------------------------------
__global__ __launch_bounds__(256) void logits_kernel(
    const float* __restrict__ wout, const float* __restrict__ bout,
    unsigned int* __restrict__ ws) {
  const float* h1f = reinterpret_cast<const float*>(ws + WS_H1F);
  float* lg = reinterpret_cast<float*>(ws + WS_LOG);
  const int lane = threadIdx.x & 63;
  const int wv = threadIdx.x >> 6;
  const int gw = blockIdx.x * 4 + wv;    // 1024 waves total
  const float4* h4 = reinterpret_cast<const float4*>(h1f);
  float4 h[4];
#pragma unroll
  for (int j = 0; j < 4; ++j) h[j] = h4[j * 64 + lane];
  for (int v = gw; v < VOCAB; v += 1024) {
    const float4* wr = reinterpret_cast<const float4*>(wout + (size_t)v * HID);
    float s = 0.f;
#pragma unroll
    for (int j = 0; j < 4; ++j) {
      float4 x = wr[j * 64 + lane];
      s += x.x * h[j].x + x.y * h[j].y + x.z * h[j].z + x.w * h[j].w;
    }
#pragma unroll
    for (int m = 32; m >= 1; m >>= 1) s += __shfl_xor(s, m, 64);
    if (lane == 0) lg[v] = s + bout[v];
  }
}

__global__ __launch_bounds__(1024) void lse_kernel(unsigned int* __restrict__ ws) {
  const float* lg = reinterpret_cast<const float*>(ws + WS_LOG);
  __shared__ float wred[16];
  __shared__ float mshare;
  const int tid = threadIdx.x;
  float m = -3.4e38f;
  for (int i = tid; i < VOCAB; i += 1024) m = fmaxf(m, lg[i]);
#pragma unroll
  for (int s = 32; s >= 1; s >>= 1) m = fmaxf(m, __shfl_xor(m, s, 64));
  if ((tid & 63) == 0) wred[tid >> 6] = m;
  __syncthreads();
  if (tid == 0) {
    float mm = wred[0];
    for (int i = 1; i < 16; ++i) mm = fmaxf(mm, wred[i]);
    mshare = mm;
  }
  __syncthreads();
  const float M = mshare;
  float a = 0.f;
  for (int i = tid; i < VOCAB; i += 1024) a += __expf(lg[i] - M);
#pragma unroll
  for (int s = 32; s >= 1; s >>= 1) a += __shfl_xor(a, s, 64);
  __syncthreads();
  if ((tid & 63) == 0) wred[tid >> 6] = a;
  __syncthreads();
  if (tid == 0) {
    float ss = 0.f;
    for (int i = 0; i < 16; ++i) ss += wred[i];
    reinterpret_cast<float*>(ws + WS_LSE)[0] = M + logf(ss);
  }
}

__global__ __launch_bounds__(256) void out_kernel(
    const unsigned int* __restrict__ ws, float* __restrict__ dout) {
  const float lse = reinterpret_cast<const float*>(ws + WS_LSE)[0];
  const float* lg = reinterpret_cast<const float*>(ws + WS_LOG);
  const int i = blockIdx.x * 256 + threadIdx.x;
  if (i < VOCAB) dout[i] = lg[i] - lse;
}

// ---------------------------------------------------------------------------
extern "C" void kernel_launch(void* const* d_in, const int* in_sizes, int n_in,
                              void* d_out, int out_size, void* d_ws, size_t ws_size,
                              hipStream_t stream) {
  const int*   tok  = (const int*)d_in[0];
  const float* h0in = (const float*)d_in[1];
  const float* c0in = (const float*)d_in[2];
  const float* emb  = (const float*)d_in[3];
  const float* wih0 = (const float*)d_in[4];
  const float* whh0 = (const float*)d_in[5];
  const float* bih0 = (const float*)d_in[6];
  const float* bhh0 = (const float*)d_in[7];
  const float* wih1 = (const float*)d_in[8];
  const float* whh1 = (const float*)d_in[9];
  const float* bih1 = (const float*)d_in[10];
  const float* bhh1 = (const float*)d_in[11];
  const float* wout = (const float*)d_in[12];
  const float* bout = (const float*)d_in[13];
  float* out = (float*)d_out;
  unsigned int* ws = (unsigned int*)d_ws;

  (void)in_sizes; (void)n_in; (void)out_size; (void)ws_size;

  (void)hipFuncSetAttribute((const void*)scan_kernel,
                            hipFuncAttributeMaxDynamicSharedMemorySize, SMEM_BYTES);

  reset_kernel<<<1, TPB, 0, stream>>>(h0in, ws);
  scan_kernel<<<NBLK, TPB, SMEM_BYTES, stream>>>(
      tok, h0in, c0in, emb, wih0, whh0, bih0, bhh0,
      wih1, whh1, bih1, bhh1, out, ws);
  logits_kernel<<<256, 256, 0, stream>>>(wout, bout, ws);
  lse_kernel<<<1, 1024, 0, stream>>>(ws);
  out_kernel<<<(VOCAB + 255) / 256, 256, 0, stream>>>(ws, out);
}

// Round 6
// 16764.653 us; speedup vs baseline: 1.1913x; 1.1913x over previous
//
#include <hip/hip_runtime.h>

// ---------------------------------------------------------------------------
// 2-layer LSTM LM forward, MI355X persistent-kernel design, round 6.
//
//   Decoupled dual pipelines, NO block barrier in the loop:
//     waves 0-1: poll h0 ring + stage x,h0 -> v0[parity]
//     wave  2  : layer0 segs 0-23 (B in VGPRs) -> partial
//     wave  3  : layer0 segs 24-47 + gates + publish h0
//     waves 4-5: poll h1 ring -> v1[parity]
//     wave  6  : layer1 segs 0-31 -> partial
//     wave  7  : layer1 segs 32-63 + gates + publish h1
//   h travels as TAG-EMBEDDED u64 ((round<<32)|bf16x2), RELAXED agent
//   atomics (R3 protocol). Intra-block sync: LDS round counters
//   (release/acquire, workgroup scope). Cross-round LDS reuse is safe via
//   the publish->poll happens-before chain; the one uncovered hazard
//   (stagers overwriting v0 while slow layer1 reads it) is gated on
//   local counters c3/pA1/c7 >= r-2.
// ---------------------------------------------------------------------------

#define T_SEQ 4096
#define HID   1024
#define EMBD  512
#define VOCAB 50257
#define NBLK  256
#define TPB   512
#define UB    4

// workspace layout (32-bit word offsets)
#define WS_H0T 0       // u64[2][512]: (tag<<32)|bf16pair
#define WS_H1T 2048    // u64[2][512]
#define WS_H1F 4096    // float[1024] final h1
#define WS_LOG 5120    // float[50257] logits
#define WS_LSE 55377   // float[1]

// LDS layout (bytes)
#define OFF_W0 0                   // short8[48*64] = 49152
#define OFF_W1 49152               // short8[64*64] = 65536
#define OFF_V0 114688              // 2 x 768 words (x(256) || h0(512))
#define OFF_V1 120832              // 2 x 512 words (h1)
#define OFF_PP0 124928             // float[2][16]
#define OFF_PP1 125056             // float[2][16]
#define OFF_B0 125184              // float[16]
#define OFF_B1 125248              // float[16]
#define OFF_FL 125312              // unsigned[16] round counters
#define SMEM_BYTES 125376

// flag indices
#define FL_SF0 0
#define FL_SF1 1
#define FL_SF4 4
#define FL_SF5 5
#define FL_PA0 8
#define FL_PA1 9
#define FL_C3  10
#define FL_C7  11

typedef __attribute__((ext_vector_type(8))) short short8;
typedef __attribute__((ext_vector_type(4))) float f32x4;
typedef unsigned long long u64;

__device__ __forceinline__ unsigned short f2bf(float f) {
  unsigned int u = __float_as_uint(f);
  u += 0x7FFFu + ((u >> 16) & 1u);          // round-to-nearest-even
  return (unsigned short)(u >> 16);
}
__device__ __forceinline__ unsigned int pack2bf(float a, float b) {
  return (unsigned int)f2bf(a) | ((unsigned int)f2bf(b) << 16);
}
__device__ __forceinline__ float sigmoidf_(float x) {
  return 1.f / (1.f + __expf(-x));
}
__device__ __forceinline__ float tanhf_(float x) {
  return 1.f - 2.f / (__expf(2.f * x) + 1.f);
}
__device__ __forceinline__ unsigned ldsacq(const unsigned* p) {
  return __hip_atomic_load(p, __ATOMIC_ACQUIRE, __HIP_MEMORY_SCOPE_WORKGROUP);
}
__device__ __forceinline__ void ldsrel(unsigned* p, unsigned v) {
  __hip_atomic_store(p, v, __ATOMIC_RELEASE, __HIP_MEMORY_SCOPE_WORKGROUP);
}
__device__ __forceinline__ u64 agld(const u64* p) {
  return __hip_atomic_load(p, __ATOMIC_RELAXED, __HIP_MEMORY_SCOPE_AGENT);
}
__device__ __forceinline__ void agst(u64* p, u64 v) {
  __hip_atomic_store(p, v, __ATOMIC_RELAXED, __HIP_MEMORY_SCOPE_AGENT);
}

// NS MFMA k-segments; B-fragments from registers, A (v) broadcast from LDS.
// Any lane->k map cancels between A and B (packed with the same map).
// D: col = lane&15 = gate-row (HW-verified C/D layout).
template<int NS>
__device__ __forceinline__ f32x4 mm_regs(const f32x4 (&fr)[NS],
                                         const short8* avb, int grp) {
  f32x4 a0 = {0.f, 0.f, 0.f, 0.f};
  f32x4 a1 = a0, a2 = a0, a3 = a0;
#pragma unroll
  for (int i = 0; i < NS; ++i) {
    short8 av = avb[i * 4 + grp];
    short8 bv = __builtin_bit_cast(short8, fr[i]);
    if ((i & 3) == 0)      a0 = __builtin_amdgcn_mfma_f32_16x16x32_bf16(av, bv, a0, 0, 0, 0);
    else if ((i & 3) == 1) a1 = __builtin_amdgcn_mfma_f32_16x16x32_bf16(av, bv, a1, 0, 0, 0);
    else if ((i & 3) == 2) a2 = __builtin_amdgcn_mfma_f32_16x16x32_bf16(av, bv, a2, 0, 0, 0);
    else                   a3 = __builtin_amdgcn_mfma_f32_16x16x32_bf16(av, bv, a3, 0, 0, 0);
  }
  return (a0 + a1) + (a2 + a3);
}

// ---------------------------------------------------------------------------
__global__ __launch_bounds__(TPB, 1) void reset_kernel(
    const float* __restrict__ h0in, unsigned int* __restrict__ ws) {
  const int tid = threadIdx.x;
  u64* H0T = reinterpret_cast<u64*>(ws + WS_H0T);
  u64* H1T = reinterpret_cast<u64*>(ws + WS_H1T);
  // slot 0 <- initial hidden states tag 0; slot 1 <- INVALID tag (kills the
  // cross-replay stale-tag race). Agent-scope so the scan's polls see them.
  const u64 w0 = (u64)pack2bf(h0in[2 * tid], h0in[2 * tid + 1]);
  const u64 w1 = (u64)pack2bf(h0in[HID + 2 * tid], h0in[HID + 2 * tid + 1]);
  agst(&H0T[tid], w0);
  agst(&H1T[tid], w1);
  agst(&H0T[512 + tid], 0xFFFFFFFF00000000ULL);
  agst(&H1T[512 + tid], 0xFFFFFFFF00000000ULL);
}

// ---------------------------------------------------------------------------
__global__ __launch_bounds__(TPB, 1) void scan_kernel(
    const int* __restrict__ tok,
    const float* __restrict__ h0in, const float* __restrict__ c0in,
    const float* __restrict__ emb,
    const float* __restrict__ wih0, const float* __restrict__ whh0,
    const float* __restrict__ bih0, const float* __restrict__ bhh0,
    const float* __restrict__ wih1, const float* __restrict__ whh1,
    const float* __restrict__ bih1, const float* __restrict__ bhh1,
    float* __restrict__ dout, unsigned int* __restrict__ ws) {
  extern __shared__ char smem[];
  short8* W0f = reinterpret_cast<short8*>(smem + OFF_W0);
  short8* W1f = reinterpret_cast<short8*>(smem + OFF_W1);
  unsigned int* v0w = reinterpret_cast<unsigned int*>(smem + OFF_V0);
  unsigned int* v1w = reinterpret_cast<unsigned int*>(smem + OFF_V1);
  const short8* v0f = reinterpret_cast<const short8*>(smem + OFF_V0);
  const short8* v1f = reinterpret_cast<const short8*>(smem + OFF_V1);
  float* pp0 = reinterpret_cast<float*>(smem + OFF_PP0);
  float* pp1 = reinterpret_cast<float*>(smem + OFF_PP1);
  float* bs0 = reinterpret_cast<float*>(smem + OFF_B0);
  float* bs1 = reinterpret_cast<float*>(smem + OFF_B1);
  unsigned* flg = reinterpret_cast<unsigned*>(smem + OFF_FL);

  const int tid = threadIdx.x;
  const int bid = blockIdx.x;
  const int lane = tid & 63;
  const int w = tid >> 6;
  const int grp = lane >> 4;

  // ---- stage weights into LDS as pre-swizzled B-fragments (bf16) ----
  for (int slot = tid; slot < 48 * 64; slot += TPB) {
    const int seg = slot >> 6, l = slot & 63;
    const int col = l & 15, g = l >> 4;
    const int grow = (col >> 2) * HID + bid * UB + (col & 3);
    const int k0 = seg * 32 + g * 8;
    const float* src = (k0 < EMBD) ? (wih0 + (size_t)grow * EMBD + k0)
                                   : (whh0 + (size_t)grow * HID + (k0 - EMBD));
    const float4* s4 = reinterpret_cast<const float4*>(src);
    float4 f0 = s4[0], f1 = s4[1];
    short8 pk;
    pk[0] = (short)f2bf(f0.x); pk[1] = (short)f2bf(f0.y);
    pk[2] = (short)f2bf(f0.z); pk[3] = (short)f2bf(f0.w);
    pk[4] = (short)f2bf(f1.x); pk[5] = (short)f2bf(f1.y);
    pk[6] = (short)f2bf(f1.z); pk[7] = (short)f2bf(f1.w);
    W0f[slot] = pk;
  }
  for (int slot = tid; slot < 64 * 64; slot += TPB) {
    const int seg = slot >> 6, l = slot & 63;
    const int col = l & 15, g = l >> 4;
    const int grow = (col >> 2) * HID + bid * UB + (col & 3);
    const int k0 = seg * 32 + g * 8;
    const float* src = (k0 < HID) ? (wih1 + (size_t)grow * HID + k0)
                                  : (whh1 + (size_t)grow * HID + (k0 - HID));
    const float4* s4 = reinterpret_cast<const float4*>(src);
    float4 f0 = s4[0], f1 = s4[1];
    short8 pk;
    pk[0] = (short)f2bf(f0.x); pk[1] = (short)f2bf(f0.y);
    pk[2] = (short)f2bf(f0.z); pk[3] = (short)f2bf(f0.w);
    pk[4] = (short)f2bf(f1.x); pk[5] = (short)f2bf(f1.y);
    pk[6] = (short)f2bf(f1.z); pk[7] = (short)f2bf(f1.w);
    W1f[slot] = pk;
  }
  if (tid < 16) {
    const int grow = (tid >> 2) * HID + bid * UB + (tid & 3);
    bs0[tid] = bih0[grow] + bhh0[grow];
  } else if (tid < 32) {
    const int c = tid - 16;
    const int grow = (c >> 2) * HID + bid * UB + (c & 3);
    bs1[c] = bih1[grow] + bhh1[grow];
  }
  if (tid < 16) flg[tid] = 0u;

  u64* H0T = reinterpret_cast<u64*>(ws + WS_H0T);
  u64* H1T = reinterpret_cast<u64*>(ws + WS_H1T);

  __syncthreads();   // weights, biases, flags ready; last barrier in kernel

  if (w < 2) {
    // ---------------- staging pipeline 0: x + h0 -> v0[parity] -----------
    const int t = tid;                                   // 0..127
    const float4* emb4 = reinterpret_cast<const float4*>(emb);
    float4 xcur = emb4[(size_t)tok[0] * 128 + t];
    for (int r = 1; r <= T_SEQ + 1; ++r) {
      const int p = r & 1;
      const int ridx = (r < T_SEQ) ? r : (T_SEQ - 1);
      float4 xnext = emb4[(size_t)tok[ridx] * 128 + t];  // overlaps the poll
      if (r >= 3) {
        // local overwrite gate: layer0 (via c3) and layer1 (pA1,c7) must be
        // done READING v0[p] from round r-2 before we overwrite it.
        const unsigned need = (unsigned)(r - 2);
        while (ldsacq(&flg[FL_C3]) < need || ldsacq(&flg[FL_PA1]) < need ||
               ldsacq(&flg[FL_C7]) < need) { }
      }
      v0w[p * 768 + 2 * t]     = pack2bf(xcur.x, xcur.y);
      v0w[p * 768 + 2 * t + 1] = pack2bf(xcur.z, xcur.w);
      const unsigned tg = (unsigned)(r - 1);
      u64* ap = &H0T[((r - 1) & 1) * 512 + 4 * t];
      u64 d0 = 0, d1 = 0, d2 = 0, d3 = 0;
      bool k0 = false, k1 = false, k2 = false, k3 = false;
      do {
        if (!k0) { d0 = agld(ap + 0); k0 = ((unsigned)(d0 >> 32) == tg); }
        if (!k1) { d1 = agld(ap + 1); k1 = ((unsigned)(d1 >> 32) == tg); }
        if (!k2) { d2 = agld(ap + 2); k2 = ((unsigned)(d2 >> 32) == tg); }
        if (!k3) { d3 = agld(ap + 3); k3 = ((unsigned)(d3 >> 32) == tg); }
      } while (!(k0 && k1 && k2 && k3));
      unsigned* dst = &v0w[p * 768 + 256 + 4 * t];
      dst[0] = (unsigned)d0; dst[1] = (unsigned)d1;
      dst[2] = (unsigned)d2; dst[3] = (unsigned)d3;
      ldsrel(&flg[w], (unsigned)r);
      xcur = xnext;
    }
  } else if (w == 2) {
    // ---------------- layer0 A: segs 0-23 ---------------------------------
    f32x4 fr[24];
    const f32x4* Wr = reinterpret_cast<const f32x4*>(W0f);
#pragma unroll
    for (int i = 0; i < 24; ++i) fr[i] = Wr[i * 64 + lane];
#pragma unroll
    for (int i = 0; i < 24; ++i) asm volatile("" : "+v"(fr[i]));  // pin in VGPRs
    for (int r = 1; r <= T_SEQ; ++r) {
      const int p = r & 1;
      const unsigned ru = (unsigned)r;
      while (ldsacq(&flg[FL_SF0]) < ru || ldsacq(&flg[FL_SF1]) < ru) { }
      f32x4 s = mm_regs<24>(fr, v0f + p * 192, grp);
      if (lane < 16) pp0[p * 16 + lane] = s[0];
      ldsrel(&flg[FL_PA0], ru);
    }
  } else if (w == 3) {
    // ---------------- layer0 B: segs 24-47 + gates + publish --------------
    f32x4 fr[24];
    const f32x4* Wr = reinterpret_cast<const f32x4*>(W0f);
#pragma unroll
    for (int i = 0; i < 24; ++i) fr[i] = Wr[(24 + i) * 64 + lane];
#pragma unroll
    for (int i = 0; i < 24; ++i) asm volatile("" : "+v"(fr[i]));
    float cst = (lane < UB) ? c0in[bid * UB + lane] : 0.f;
    for (int r = 1; r <= T_SEQ; ++r) {
      const int p = r & 1;
      const unsigned ru = (unsigned)r;
      while (ldsacq(&flg[FL_SF0]) < ru || ldsacq(&flg[FL_SF1]) < ru) { }
      f32x4 s = mm_regs<24>(fr, v0f + p * 192 + 96, grp);
      ldsrel(&flg[FL_C3], ru);               // v0[p] reads done (lgkm drained)
      while (ldsacq(&flg[FL_PA0]) < ru) { }
      float g = 0.f;
      if (lane < 16) g = s[0] + pp0[p * 16 + lane] + bs0[lane];
      const int u = lane & 3;
      const float gi = __shfl(g, u),      gf = __shfl(g, 4 + u);
      const float gg = __shfl(g, 8 + u),  go = __shfl(g, 12 + u);
      float hv = 0.f;
      if (lane < UB) {
        const float c = sigmoidf_(gf) * cst + sigmoidf_(gi) * tanhf_(gg);
        cst = c;
        hv = sigmoidf_(go) * tanhf_(c);
        if (r == T_SEQ) {
          dout[VOCAB + bid * UB + lane] = hv;             // h_n layer0
          dout[VOCAB + 2 * HID + bid * UB + lane] = c;    // c_n layer0
        }
      }
      const float a = __shfl(hv, 2 * (lane & 1));
      const float b = __shfl(hv, 2 * (lane & 1) + 1);
      if (lane < 2)
        agst(&H0T[(r & 1) * 512 + bid * 2 + lane],
             ((u64)ru << 32) | (u64)pack2bf(a, b));
    }
  } else if (w < 6) {
    // ---------------- staging pipeline 1: h1 -> v1[parity] ----------------
    const int t = tid - 256;                              // 0..127
    for (int r = 2; r <= T_SEQ + 1; ++r) {
      const int p = r & 1;
      const unsigned tg = (unsigned)(r - 2);
      u64* ap = &H1T[p * 512 + 4 * t];                    // (r-2)&1 == r&1
      u64 d0 = 0, d1 = 0, d2 = 0, d3 = 0;
      bool k0 = false, k1 = false, k2 = false, k3 = false;
      do {
        if (!k0) { d0 = agld(ap + 0); k0 = ((unsigned)(d0 >> 32) == tg); }
        if (!k1) { d1 = agld(ap + 1); k1 = ((unsigned)(d1 >> 32) == tg); }
        if (!k2) { d2 = agld(ap + 2); k2 = ((unsigned)(d2 >> 32) == tg); }
        if (!k3) { d3 = agld(ap + 3); k3 = ((unsigned)(d3 >> 32) == tg); }
      } while (!(k0 && k1 && k2 && k3));
      unsigned* dst = &v1w[p * 512 + 4 * t];
      dst[0] = (unsigned)d0; dst[1] = (unsigned)d1;
      dst[2] = (unsigned)d2; dst[3] = (unsigned)d3;
      ldsrel(&flg[w], (unsigned)r);
    }
  } else if (w == 6) {
    // ---------------- layer1 A: segs 0-31 (h0 half, reads v0) -------------
    f32x4 fr[32];
    const f32x4* Wr = reinterpret_cast<const f32x4*>(W1f);
#pragma unroll
    for (int i = 0; i < 32; ++i) fr[i] = Wr[i * 64 + lane];
#pragma unroll
    for (int i = 0; i < 32; ++i) asm volatile("" : "+v"(fr[i]));
    for (int r = 2; r <= T_SEQ + 1; ++r) {
      const int p = r & 1;
      const unsigned ru = (unsigned)r;
      while (ldsacq(&flg[FL_SF0]) < ru || ldsacq(&flg[FL_SF1]) < ru ||
             ldsacq(&flg[FL_SF4]) < ru || ldsacq(&flg[FL_SF5]) < ru) { }
      f32x4 s = mm_regs<32>(fr, v0f + p * 192 + 64, grp);   // h0 region of v0
      if (lane < 16) pp1[p * 16 + lane] = s[0];
      ldsrel(&flg[FL_PA1], ru);
    }
  } else {
    // ---------------- layer1 B: segs 32-63 + gates + publish --------------
    f32x4 fr[32];
    const f32x4* Wr = reinterpret_cast<const f32x4*>(W1f);
#pragma unroll
    for (int i = 0; i < 32; ++i) fr[i] = Wr[(32 + i) * 64 + lane];
#pragma unroll
    for (int i = 0; i < 32; ++i) asm volatile("" : "+v"(fr[i]));
    float cst = (lane < UB) ? c0in[HID + bid * UB + lane] : 0.f;
    for (int r = 2; r <= T_SEQ + 1; ++r) {
      const int p = r & 1;
      const unsigned ru = (unsigned)r;
      while (ldsacq(&flg[FL_SF0]) < ru || ldsacq(&flg[FL_SF1]) < ru ||
             ldsacq(&flg[FL_SF4]) < ru || ldsacq(&flg[FL_SF5]) < ru) { }
      f32x4 s = mm_regs<32>(fr, v1f + p * 128, grp);        // h1 half
      ldsrel(&flg[FL_C7], ru);               // v reads done
      while (ldsacq(&flg[FL_PA1]) < ru) { }
      float g = 0.f;
      if (lane < 16) g = s[0] + pp1[p * 16 + lane] + bs1[lane];
      const int u = lane & 3;
      const float gi = __shfl(g, u),      gf = __shfl(g, 4 + u);
      const float gg = __shfl(g, 8 + u),  go = __shfl(g, 12 + u);
      float hv = 0.f;
      if (lane < UB) {
        const float c = sigmoidf_(gf) * cst + sigmoidf_(gi) * tanhf_(gg);
        cst = c;
        hv = sigmoidf_(go) * tanhf_(c);
        if (r == T_SEQ + 1) {
          float* h1f = reinterpret_cast<float*>(ws + WS_H1F);
          h1f[bid * UB + lane] = hv;
          dout[VOCAB + HID + bid * UB + lane] = hv;          // h_n layer1
          dout[VOCAB + 3 * HID + bid * UB + lane] = c;       // c_n layer1
        }
      }
      const float a = __shfl(hv, 2 * (lane & 1));
      const float b = __shfl(hv, 2 * (lane & 1) + 1);
      if (lane < 2)
        agst(&H1T[((r - 1) & 1) * 512 + bid * 2 + lane],
             ((u64)(unsigned)(r - 1) << 32) | (u64)pack2bf(a, b));
    }
  }
}

// ---------------------------------------------------------------------------
__global__ __launch_bounds__(256) void logits_kernel(
    const float* __restrict__ wout, const float* __restrict__ bout,
    unsigned int* __restrict__ ws) {
  const float* h1f = reinterpret_cast<const float*>(ws + WS_H1F);
  float* lg = reinterpret_cast<float*>(ws + WS_LOG);
  const int lane = threadIdx.x & 63;
  const int wv = threadIdx.x >> 6;
  const int gw = blockIdx.x * 4 + wv;    // 1024 waves total
  const float4* h4 = reinterpret_cast<const float4*>(h1f);
  float4 h[4];
#pragma unroll
  for (int j = 0; j < 4; ++j) h[j] = h4[j * 64 + lane];
  for (int v = gw; v < VOCAB; v += 1024) {
    const float4* wr = reinterpret_cast<const float4*>(wout + (size_t)v * HID);
    float s = 0.f;
#pragma unroll
    for (int j = 0; j < 4; ++j) {
      float4 x = wr[j * 64 + lane];
      s += x.x * h[j].x + x.y * h[j].y + x.z * h[j].z + x.w * h[j].w;
    }
#pragma unroll
    for (int m = 32; m >= 1; m >>= 1) s += __shfl_xor(s, m, 64);
    if (lane == 0) lg[v] = s + bout[v];
  }
}

__global__ __launch_bounds__(1024) void lse_kernel(unsigned int* __restrict__ ws) {
  const float* lg = reinterpret_cast<const float*>(ws + WS_LOG);
  __shared__ float wred[16];
  __shared__ float mshare;
  const int tid = threadIdx.x;
  float m = -3.4e38f;
  for (int i = tid; i < VOCAB; i += 1024) m = fmaxf(m, lg[i]);
#pragma unroll
  for (int s = 32; s >= 1; s >>= 1) m = fmaxf(m, __shfl_xor(m, s, 64));
  if ((tid & 63) == 0) wred[tid >> 6] = m;
  __syncthreads();
  if (tid == 0) {
    float mm = wred[0];
    for (int i = 1; i < 16; ++i) mm = fmaxf(mm, wred[i]);
    mshare = mm;
  }
  __syncthreads();
  const float M = mshare;
  float a = 0.f;
  for (int i = tid; i < VOCAB; i += 1024) a += __expf(lg[i] - M);
#pragma unroll
  for (int s = 32; s >= 1; s >>= 1) a += __shfl_xor(a, s, 64);
  __syncthreads();
  if ((tid & 63) == 0) wred[tid >> 6] = a;
  __syncthreads();
  if (tid == 0) {
    float ss = 0.f;
    for (int i = 0; i < 16; ++i) ss += wred[i];
    reinterpret_cast<float*>(ws + WS_LSE)[0] = M + logf(ss);
  }
}

__global__ __launch_bounds__(256) void out_kernel(
    const unsigned int* __restrict__ ws, float* __restrict__ dout) {
  const float lse = reinterpret_cast<const float*>(ws + WS_LSE)[0];
  const float* lg = reinterpret_cast<const float*>(ws + WS_LOG);
  const int i = blockIdx.x * 256 + threadIdx.x;
  if (i < VOCAB) dout[i] = lg[i] - lse;
}

// ---------------------------------------------------------------------------
extern "C" void kernel_launch(void* const* d_in, const int* in_sizes, int n_in,
                              void* d_out, int out_size, void* d_ws, size_t ws_size,
                              hipStream_t stream) {
  const int*   tok  = (const int*)d_in[0];
  const float* h0in = (const float*)d_in[1];
  const float* c0in = (const float*)d_in[2];
  const float* emb  = (const float*)d_in[3];
  const float* wih0 = (const float*)d_in[4];
  const float* whh0 = (const float*)d_in[5];
  const float* bih0 = (const float*)d_in[6];
  const float* bhh0 = (const float*)d_in[7];
  const float* wih1 = (const float*)d_in[8];
  const float* whh1 = (const float*)d_in[9];
  const float* bih1 = (const float*)d_in[10];
  const float* bhh1 = (const float*)d_in[11];
  const float* wout = (const float*)d_in[12];
  const float* bout = (const float*)d_in[13];
  float* out = (float*)d_out;
  unsigned int* ws = (unsigned int*)d_ws;

  (void)in_sizes; (void)n_in; (void)out_size; (void)ws_size;

  (void)hipFuncSetAttribute((const void*)scan_kernel,
                            hipFuncAttributeMaxDynamicSharedMemorySize, SMEM_BYTES);

  reset_kernel<<<1, TPB, 0, stream>>>(h0in, ws);
  scan_kernel<<<NBLK, TPB, SMEM_BYTES, stream>>>(
      tok, h0in, c0in, emb, wih0, whh0, bih0, bhh0,
      wih1, whh1, bih1, bhh1, out, ws);
  logits_kernel<<<256, 256, 0, stream>>>(wout, bout, ws);
  lse_kernel<<<1, 1024, 0, stream>>>(ws);
  out_kernel<<<(VOCAB + 255) / 256, 256, 0, stream>>>(ws, out);
}

// Round 7
// 13355.287 us; speedup vs baseline: 1.4954x; 1.2553x over previous
//
#include <hip/hip_runtime.h>

// ---------------------------------------------------------------------------
// 2-layer LSTM LM forward, MI355X persistent-kernel design, round 7.
//
//   Minimal-critical-path: ONE wave (wave0) owns the whole layer-0 recurrence
//   (poll h0 -> stage -> 48 MFMAs -> gates -> publish), no barriers and no
//   cross-wave waits on that path. Layer 1 (1-round slack, off-path) runs on
//   waves 2-3, fed through LDS flags; wave 1 polls the h1 ring.
//
//   TPB=256 -> 4 waves, 1 per SIMD. h travels as TAG-EMBEDDED u64
//   ((round<<32)|bf16x2), RELAXED agent atomics (R3 protocol, proven).
//   Rings double-buffered by round parity; slot-1 invalidated at reset
//   (cross-replay stale-tag fix).
//
//   round r: layer0 computes step r (x_r = emb[tok[r-1]]), publishes tag r;
//            layer1 computes step r-1 from h0(r-1), h1(r-2), publishes r-1.
// ---------------------------------------------------------------------------

#define T_SEQ 4096
#define HID   1024
#define EMBD  512
#define VOCAB 50257
#define NBLK  256
#define TPB   256
#define UB    4

// workspace layout (32-bit word offsets)
#define WS_H0T 0       // u64[2][512]: (tag<<32)|bf16pair
#define WS_H1T 2048    // u64[2][512]
#define WS_H1F 4096    // float[1024] final h1
#define WS_LOG 5120    // float[50257] logits
#define WS_LSE 55377   // float[1]

// LDS layout (bytes)
#define OFF_W0 0                   // short8[48*64] = 49152
#define OFF_W1 49152               // short8[64*64] = 65536
#define OFF_V0 114688              // 2 x 768 u32  (x(256w) || h0(512w))
#define OFF_V1 120832              // 2 x 512 u32  (h1)
#define OFF_PP 124928              // float[2][16] layer1 partials
#define OFF_FL 125056              // unsigned[8] flags
#define SMEM_BYTES 125088

// flag indices
#define FL_SF0 0   // wave0: v0[r&1] staged for round r
#define FL_SF1 1   // wave1: v1[r&1] staged for round r
#define FL_PA1 2   // wave2: layer1 partial A done round r (also: v0 reads done)
#define FL_C3  3   // wave3: v1 reads done round r

typedef __attribute__((ext_vector_type(8))) short short8;
typedef __attribute__((ext_vector_type(4))) float f32x4;
typedef unsigned long long u64;

__device__ __forceinline__ unsigned short f2bf(float f) {
  unsigned int u = __float_as_uint(f);
  u += 0x7FFFu + ((u >> 16) & 1u);          // round-to-nearest-even
  return (unsigned short)(u >> 16);
}
__device__ __forceinline__ unsigned int pack2bf(float a, float b) {
  return (unsigned int)f2bf(a) | ((unsigned int)f2bf(b) << 16);
}
__device__ __forceinline__ float sigmoidf_(float x) {
  return 1.f / (1.f + __expf(-x));
}
__device__ __forceinline__ float tanhf_(float x) {
  return 1.f - 2.f / (__expf(2.f * x) + 1.f);
}
__device__ __forceinline__ unsigned ldsacq(const unsigned* p) {
  return __hip_atomic_load(p, __ATOMIC_ACQUIRE, __HIP_MEMORY_SCOPE_WORKGROUP);
}
__device__ __forceinline__ void ldsrel(unsigned* p, unsigned v) {
  __hip_atomic_store(p, v, __ATOMIC_RELEASE, __HIP_MEMORY_SCOPE_WORKGROUP);
}
__device__ __forceinline__ u64 agld(const u64* p) {
  return __hip_atomic_load(p, __ATOMIC_RELAXED, __HIP_MEMORY_SCOPE_AGENT);
}
__device__ __forceinline__ void agst(u64* p, u64 v) {
  __hip_atomic_store(p, v, __ATOMIC_RELAXED, __HIP_MEMORY_SCOPE_AGENT);
}

// NS MFMA k-segments; A = v broadcast from LDS, B = weight frags from LDS
// (R3 pattern: wf[i*64+lane] is 1KB/wave contiguous, conflict-free).
// Any lane->k map cancels between A and B. D: col = lane&15 = gate-row.
template<int NS>
__device__ __forceinline__ f32x4 mm_lds(const short8* vf, const short8* wf,
                                        int grp, int lane) {
  f32x4 a0 = {0.f, 0.f, 0.f, 0.f};
  f32x4 a1 = a0, a2 = a0, a3 = a0;
#pragma unroll
  for (int i = 0; i < NS; ++i) {
    short8 av = vf[i * 4 + grp];
    short8 bv = wf[i * 64 + lane];
    if ((i & 3) == 0)      a0 = __builtin_amdgcn_mfma_f32_16x16x32_bf16(av, bv, a0, 0, 0, 0);
    else if ((i & 3) == 1) a1 = __builtin_amdgcn_mfma_f32_16x16x32_bf16(av, bv, a1, 0, 0, 0);
    else if ((i & 3) == 2) a2 = __builtin_amdgcn_mfma_f32_16x16x32_bf16(av, bv, a2, 0, 0, 0);
    else                   a3 = __builtin_amdgcn_mfma_f32_16x16x32_bf16(av, bv, a3, 0, 0, 0);
  }
  return (a0 + a1) + (a2 + a3);
}

// ---------------------------------------------------------------------------
__global__ __launch_bounds__(512, 1) void reset_kernel(
    const float* __restrict__ h0in, unsigned int* __restrict__ ws) {
  const int tid = threadIdx.x;
  u64* H0T = reinterpret_cast<u64*>(ws + WS_H0T);
  u64* H1T = reinterpret_cast<u64*>(ws + WS_H1T);
  // slot 0 <- initial hidden states tag 0; slot 1 <- INVALID tag (kills the
  // cross-replay stale-tag race). Agent-scope so the scan's polls see them.
  agst(&H0T[tid], (u64)pack2bf(h0in[2 * tid], h0in[2 * tid + 1]));
  agst(&H1T[tid], (u64)pack2bf(h0in[HID + 2 * tid], h0in[HID + 2 * tid + 1]));
  agst(&H0T[512 + tid], 0xFFFFFFFF00000000ULL);
  agst(&H1T[512 + tid], 0xFFFFFFFF00000000ULL);
}

// ---------------------------------------------------------------------------
__global__ __launch_bounds__(TPB, 1) void scan_kernel(
    const int* __restrict__ tok,
    const float* __restrict__ h0in, const float* __restrict__ c0in,
    const float* __restrict__ emb,
    const float* __restrict__ wih0, const float* __restrict__ whh0,
    const float* __restrict__ bih0, const float* __restrict__ bhh0,
    const float* __restrict__ wih1, const float* __restrict__ whh1,
    const float* __restrict__ bih1, const float* __restrict__ bhh1,
    float* __restrict__ dout, unsigned int* __restrict__ ws) {
  extern __shared__ char smem[];
  short8* W0f = reinterpret_cast<short8*>(smem + OFF_W0);
  short8* W1f = reinterpret_cast<short8*>(smem + OFF_W1);
  unsigned int* v0w = reinterpret_cast<unsigned int*>(smem + OFF_V0);
  unsigned int* v1w = reinterpret_cast<unsigned int*>(smem + OFF_V1);
  const short8* v0f = reinterpret_cast<const short8*>(smem + OFF_V0);
  const short8* v1f = reinterpret_cast<const short8*>(smem + OFF_V1);
  float* pp  = reinterpret_cast<float*>(smem + OFF_PP);
  unsigned* flg = reinterpret_cast<unsigned*>(smem + OFF_FL);

  const int tid = threadIdx.x;
  const int bid = blockIdx.x;
  const int lane = tid & 63;
  const int w = tid >> 6;
  const int grp = lane >> 4;

  // ---- stage weights into LDS as pre-swizzled B-fragments (bf16) ----
  for (int slot = tid; slot < 48 * 64; slot += TPB) {
    const int seg = slot >> 6, l = slot & 63;
    const int col = l & 15, g = l >> 4;
    const int grow = (col >> 2) * HID + bid * UB + (col & 3);
    const int k0 = seg * 32 + g * 8;
    const float* src = (k0 < EMBD) ? (wih0 + (size_t)grow * EMBD + k0)
                                   : (whh0 + (size_t)grow * HID + (k0 - EMBD));
    const float4* s4 = reinterpret_cast<const float4*>(src);
    float4 f0 = s4[0], f1 = s4[1];
    short8 pk;
    pk[0] = (short)f2bf(f0.x); pk[1] = (short)f2bf(f0.y);
    pk[2] = (short)f2bf(f0.z); pk[3] = (short)f2bf(f0.w);
    pk[4] = (short)f2bf(f1.x); pk[5] = (short)f2bf(f1.y);
    pk[6] = (short)f2bf(f1.z); pk[7] = (short)f2bf(f1.w);
    W0f[slot] = pk;
  }
  for (int slot = tid; slot < 64 * 64; slot += TPB) {
    const int seg = slot >> 6, l = slot & 63;
    const int col = l & 15, g = l >> 4;
    const int grow = (col >> 2) * HID + bid * UB + (col & 3);
    const int k0 = seg * 32 + g * 8;
    const float* src = (k0 < HID) ? (wih1 + (size_t)grow * HID + k0)
                                  : (whh1 + (size_t)grow * HID + (k0 - HID));
    const float4* s4 = reinterpret_cast<const float4*>(src);
    float4 f0 = s4[0], f1 = s4[1];
    short8 pk;
    pk[0] = (short)f2bf(f0.x); pk[1] = (short)f2bf(f0.y);
    pk[2] = (short)f2bf(f0.z); pk[3] = (short)f2bf(f0.w);
    pk[4] = (short)f2bf(f1.x); pk[5] = (short)f2bf(f1.y);
    pk[6] = (short)f2bf(f1.z); pk[7] = (short)f2bf(f1.w);
    W1f[slot] = pk;
  }
  if (tid < 8) flg[tid] = 1u;   // "rounds <= 1 complete" for lag-2 gates

  u64* H0T = reinterpret_cast<u64*>(ws + WS_H0T);
  u64* H1T = reinterpret_cast<u64*>(ws + WS_H1T);

  __syncthreads();   // weights + flags ready; the last barrier in the kernel

  if (w == 0) {
    // ============ wave 0: the ENTIRE layer-0 recurrence =====================
    // per-lane bias (lanes 0-15), cell state (lanes 0-3)
    float bs0 = 0.f;
    if (lane < 16) {
      const int grow = (lane >> 2) * HID + bid * UB + (lane & 3);
      bs0 = bih0[grow] + bhh0[grow];
    }
    float cst = (lane < UB) ? c0in[bid * UB + lane] : 0.f;

    // x prefetch for round 1 (8 floats/lane -> 2 packed u64)
    const float4* e4 = reinterpret_cast<const float4*>(emb) + (size_t)tok[0] * 128;
    float4 xA = e4[lane], xB = e4[64 + lane];

    for (int r = 1; r <= T_SEQ + 1; ++r) {
      const int p = r & 1;
      // lag-2 overwrite gate: wave2 must be done reading v0[p] (round r-2)
      if (r >= 3) {
        const unsigned need = (unsigned)(r - 2);
        while (ldsacq(&flg[FL_PA1]) < need) { }
      }
      // write x_r (loaded last round) into v0[p]; prefetch x_{r+1}
      if (r <= T_SEQ) {
        u64* vx = reinterpret_cast<u64*>(v0w + p * 768);
        vx[lane]      = (u64)pack2bf(xA.x, xA.y) | ((u64)pack2bf(xA.z, xA.w) << 32);
        vx[64 + lane] = (u64)pack2bf(xB.x, xB.y) | ((u64)pack2bf(xB.z, xB.w) << 32);
        if (r <= T_SEQ - 1) {
          const float4* en = reinterpret_cast<const float4*>(emb) + (size_t)tok[r] * 128;
          xA = en[lane]; xB = en[64 + lane];
        }
      }
      // poll h0(r-1): 8 tagged u64 per lane
      {
        const unsigned tg = (unsigned)(r - 1);
        const u64* ap = &H0T[((r - 1) & 1) * 512 + lane];
        u64 d0, d1, d2, d3, d4, d5, d6, d7;
        for (;;) {
          d0 = agld(ap);        d1 = agld(ap + 64);  d2 = agld(ap + 128);
          d3 = agld(ap + 192);  d4 = agld(ap + 256); d5 = agld(ap + 320);
          d6 = agld(ap + 384);  d7 = agld(ap + 448);
          if ((unsigned)(d0 >> 32) == tg && (unsigned)(d1 >> 32) == tg &&
              (unsigned)(d2 >> 32) == tg && (unsigned)(d3 >> 32) == tg &&
              (unsigned)(d4 >> 32) == tg && (unsigned)(d5 >> 32) == tg &&
              (unsigned)(d6 >> 32) == tg && (unsigned)(d7 >> 32) == tg) break;
        }
        unsigned* dst = v0w + p * 768 + 256 + lane;
        dst[0] = (unsigned)d0;   dst[64] = (unsigned)d1;
        dst[128] = (unsigned)d2; dst[192] = (unsigned)d3;
        dst[256] = (unsigned)d4; dst[320] = (unsigned)d5;
        dst[384] = (unsigned)d6; dst[448] = (unsigned)d7;
      }
      ldsrel(&flg[FL_SF0], (unsigned)r);   // layer1 (wave2) may start

      if (r <= T_SEQ) {
        // 48-seg matvec + gates + publish — all inside this wave
        f32x4 s = mm_lds<48>(v0f + p * 192, W0f, grp, lane);
        float g = (lane < 16) ? (s[0] + bs0) : 0.f;
        const int u = lane & 3;
        const float gi = __shfl(g, u),      gf = __shfl(g, 4 + u);
        const float gg = __shfl(g, 8 + u),  go = __shfl(g, 12 + u);
        float hv = 0.f;
        if (lane < UB) {
          const float c = sigmoidf_(gf) * cst + sigmoidf_(gi) * tanhf_(gg);
          cst = c;
          hv = sigmoidf_(go) * tanhf_(c);
          if (r == T_SEQ) {
            dout[VOCAB + bid * UB + lane] = hv;             // h_n layer0
            dout[VOCAB + 2 * HID + bid * UB + lane] = c;    // c_n layer0
          }
        }
        const float a = __shfl(hv, 2 * (lane & 1));
        const float b = __shfl(hv, 2 * (lane & 1) + 1);
        if (lane < 2)
          agst(&H0T[(r & 1) * 512 + bid * 2 + lane],
               ((u64)(unsigned)r << 32) | (u64)pack2bf(a, b));
      }
      // r == T_SEQ+1: stage-only (feeds layer1's final step), no publish
    }
  } else if (w == 1) {
    // ============ wave 1: h1 ring poller ====================================
    for (int r = 2; r <= T_SEQ + 1; ++r) {
      const int p = r & 1;
      if (r >= 4) {                       // lag-2 gate: wave3 done with v1[p]
        const unsigned need = (unsigned)(r - 2);
        while (ldsacq(&flg[FL_C3]) < need) { }
      }
      const unsigned tg = (unsigned)(r - 2);
      const u64* ap = &H1T[p * 512 + lane];   // (r-2)&1 == r&1
      u64 d0, d1, d2, d3, d4, d5, d6, d7;
      for (;;) {
        d0 = agld(ap);        d1 = agld(ap + 64);  d2 = agld(ap + 128);
        d3 = agld(ap + 192);  d4 = agld(ap + 256); d5 = agld(ap + 320);
        d6 = agld(ap + 384);  d7 = agld(ap + 448);
        if ((unsigned)(d0 >> 32) == tg && (unsigned)(d1 >> 32) == tg &&
            (unsigned)(d2 >> 32) == tg && (unsigned)(d3 >> 32) == tg &&
            (unsigned)(d4 >> 32) == tg && (unsigned)(d5 >> 32) == tg &&
            (unsigned)(d6 >> 32) == tg && (unsigned)(d7 >> 32) == tg) break;
      }
      unsigned* dst = v1w + p * 512 + lane;
      dst[0] = (unsigned)d0;   dst[64] = (unsigned)d1;
      dst[128] = (unsigned)d2; dst[192] = (unsigned)d3;
      dst[256] = (unsigned)d4; dst[320] = (unsigned)d5;
      dst[384] = (unsigned)d6; dst[448] = (unsigned)d7;
      ldsrel(&flg[FL_SF1], (unsigned)r);
    }
  } else if (w == 2) {
    // ============ wave 2: layer-1 partial A (h0 half, reads v0) =============
    for (int r = 2; r <= T_SEQ + 1; ++r) {
      const int p = r & 1;
      const unsigned ru = (unsigned)r;
      while (ldsacq(&flg[FL_SF0]) < ru) { }
      f32x4 s = mm_lds<32>(v0f + p * 192 + 64, W1f, grp, lane);
      if (lane < 16) pp[p * 16 + lane] = s[0];
      ldsrel(&flg[FL_PA1], ru);     // partial ready AND v0[p] reads done
    }
  } else {
    // ============ wave 3: layer-1 partial B (h1 half) + gates + publish =====
    float bs1 = 0.f;
    if (lane < 16) {
      const int grow = (lane >> 2) * HID + bid * UB + (lane & 3);
      bs1 = bih1[grow] + bhh1[grow];
    }
    float cst = (lane < UB) ? c0in[HID + bid * UB + lane] : 0.f;
    for (int r = 2; r <= T_SEQ + 1; ++r) {
      const int p = r & 1;
      const unsigned ru = (unsigned)r;
      while (ldsacq(&flg[FL_SF1]) < ru) { }
      f32x4 s = mm_lds<32>(v1f + p * 128, W1f + 32 * 64, grp, lane);
      ldsrel(&flg[FL_C3], ru);                 // v1[p] reads done
      while (ldsacq(&flg[FL_PA1]) < ru) { }
      float g = (lane < 16) ? (s[0] + pp[p * 16 + lane] + bs1) : 0.f;
      const int u = lane & 3;
      const float gi = __shfl(g, u),      gf = __shfl(g, 4 + u);
      const float gg = __shfl(g, 8 + u),  go = __shfl(g, 12 + u);
      float hv = 0.f;
      if (lane < UB) {
        const float c = sigmoidf_(gf) * cst + sigmoidf_(gi) * tanhf_(gg);
        cst = c;
        hv = sigmoidf_(go) * tanhf_(c);
        if (r == T_SEQ + 1) {
          float* h1f = reinterpret_cast<float*>(ws + WS_H1F);
          h1f[bid * UB + lane] = hv;
          dout[VOCAB + HID + bid * UB + lane] = hv;          // h_n layer1
          dout[VOCAB + 3 * HID + bid * UB + lane] = c;       // c_n layer1
        }
      }
      const float a = __shfl(hv, 2 * (lane & 1));
      const float b = __shfl(hv, 2 * (lane & 1) + 1);
      if (lane < 2)
        agst(&H1T[((r - 1) & 1) * 512 + bid * 2 + lane],
             ((u64)(unsigned)(r - 1) << 32) | (u64)pack2bf(a, b));
    }
  }
}

// ---------------------------------------------------------------------------
__global__ __launch_bounds__(256) void logits_kernel(
    const float* __restrict__ wout, const float* __restrict__ bout,
    unsigned int* __restrict__ ws) {
  const float* h1f = reinterpret_cast<const float*>(ws + WS_H1F);
  float* lg = reinterpret_cast<float*>(ws + WS_LOG);
  const int lane = threadIdx.x & 63;
  const int wv = threadIdx.x >> 6;
  const int gw = blockIdx.x * 4 + wv;    // 1024 waves total
  const float4* h4 = reinterpret_cast<const float4*>(h1f);
  float4 h[4];
#pragma unroll
  for (int j = 0; j < 4; ++j) h[j] = h4[j * 64 + lane];
  for (int v = gw; v < VOCAB; v += 1024) {
    const float4* wr = reinterpret_cast<const float4*>(wout + (size_t)v * HID);
    float s = 0.f;
#pragma unroll
    for (int j = 0; j < 4; ++j) {
      float4 x = wr[j * 64 + lane];
      s += x.x * h[j].x + x.y * h[j].y + x.z * h[j].z + x.w * h[j].w;
    }
#pragma unroll
    for (int m = 32; m >= 1; m >>= 1) s += __shfl_xor(s, m, 64);
    if (lane == 0) lg[v] = s + bout[v];
  }
}

__global__ __launch_bounds__(1024) void lse_kernel(unsigned int* __restrict__ ws) {
  const float* lg = reinterpret_cast<const float*>(ws + WS_LOG);
  __shared__ float wred[16];
  __shared__ float mshare;
  const int tid = threadIdx.x;
  float m = -3.4e38f;
  for (int i = tid; i < VOCAB; i += 1024) m = fmaxf(m, lg[i]);
#pragma unroll
  for (int s = 32; s >= 1; s >>= 1) m = fmaxf(m, __shfl_xor(m, s, 64));
  if ((tid & 63) == 0) wred[tid >> 6] = m;
  __syncthreads();
  if (tid == 0) {
    float mm = wred[0];
    for (int i = 1; i < 16; ++i) mm = fmaxf(mm, wred[i]);
    mshare = mm;
  }
  __syncthreads();
  const float M = mshare;
  float a = 0.f;
  for (int i = tid; i < VOCAB; i += 1024) a += __expf(lg[i] - M);
#pragma unroll
  for (int s = 32; s >= 1; s >>= 1) a += __shfl_xor(a, s, 64);
  __syncthreads();
  if ((tid & 63) == 0) wred[tid >> 6] = a;
  __syncthreads();
  if (tid == 0) {
    float ss = 0.f;
    for (int i = 0; i < 16; ++i) ss += wred[i];
    reinterpret_cast<float*>(ws + WS_LSE)[0] = M + logf(ss);
  }
}

__global__ __launch_bounds__(256) void out_kernel(
    const unsigned int* __restrict__ ws, float* __restrict__ dout) {
  const float lse = reinterpret_cast<const float*>(ws + WS_LSE)[0];
  const float* lg = reinterpret_cast<const float*>(ws + WS_LOG);
  const int i = blockIdx.x * 256 + threadIdx.x;
  if (i < VOCAB) dout[i] = lg[i] - lse;
}

// ---------------------------------------------------------------------------
extern "C" void kernel_launch(void* const* d_in, const int* in_sizes, int n_in,
                              void* d_out, int out_size, void* d_ws, size_t ws_size,
                              hipStream_t stream) {
  const int*   tok  = (const int*)d_in[0];
  const float* h0in = (const float*)d_in[1];
  const float* c0in = (const float*)d_in[2];
  const float* emb  = (const float*)d_in[3];
  const float* wih0 = (const float*)d_in[4];
  const float* whh0 = (const float*)d_in[5];
  const float* bih0 = (const float*)d_in[6];
  const float* bhh0 = (const float*)d_in[7];
  const float* wih1 = (const float*)d_in[8];
  const float* whh1 = (const float*)d_in[9];
  const float* bih1 = (const float*)d_in[10];
  const float* bhh1 = (const float*)d_in[11];
  const float* wout = (const float*)d_in[12];
  const float* bout = (const float*)d_in[13];
  float* out = (float*)d_out;
  unsigned int* ws = (unsigned int*)d_ws;

  (void)in_sizes; (void)n_in; (void)out_size; (void)ws_size;

  (void)hipFuncSetAttribute((const void*)scan_kernel,
                            hipFuncAttributeMaxDynamicSharedMemorySize, SMEM_BYTES);

  reset_kernel<<<1, 512, 0, stream>>>(h0in, ws);
  scan_kernel<<<NBLK, TPB, SMEM_BYTES, stream>>>(
      tok, h0in, c0in, emb, wih0, whh0, bih0, bhh0,
      wih1, whh1, bih1, bhh1, out, ws);
  logits_kernel<<<256, 256, 0, stream>>>(wout, bout, ws);
  lse_kernel<<<1, 1024, 0, stream>>>(ws);
  out_kernel<<<(VOCAB + 255) / 256, 256, 0, stream>>>(ws, out);
}